// Round 3
// baseline (743.764 us; speedup 1.0000x reference)
//
#include <hip/hip_runtime.h>

typedef __bf16 bf16x8 __attribute__((ext_vector_type(8)));
typedef __bf16 bf16x4 __attribute__((ext_vector_type(4)));
typedef float  f32x4  __attribute__((ext_vector_type(4)));

#define MFMA16(a, b, c) __builtin_amdgcn_mfma_f32_16x16x32_bf16((a), (b), (c), 0, 0, 0)

__device__ __forceinline__ float sigm(float x) { return 1.0f / (1.0f + __expf(-x)); }

// ---- packed bf16 weight layout (element offsets inside d_ws) ----
enum : int {
  ENC_W0_OFF  = 0,        // 16 x 128 x 256
  ENC_W1_OFF  = 524288,   // 16 x 64 x 128
  ENC_W2_OFF  = 655360,   // 16 x 32 x 64
  DEC_W0_OFF  = 688128,   // 16 x 64 x 32
  DEC_W1_OFF  = 720896,   // 16 x 128 x 64
  DEC_W2_OFF  = 851968,   // 16 x 256 x 128
  COMP_W0_OFF = 1376256,  // 256 x 512  (folded [z,z])
  COMP_W1_OFF = 1507328,  // 128 x 768
  COMP_W2_OFF = 1605632,  // 64 x 640
  COMP_W3_OFF = 1646592,  // 32 x 576
  COMP_W4_OFF = 1665024,  // 16 x 544
  COMP_W5_OFF = 1673728,  // 32 x 544  (528 padded to 544, pad = 0)
  DCMP_W0_OFF = 1691136,  // 256 x 32  (folded)
  DCMP_W1_OFF = 1699328,  // 128 x 288
  DCMP_W2_OFF = 1736192,  // 64 x 160
  DCMP_W3_OFF = 1746432,  // 32 x 96
  DCMP_W4_OFF = 1749504,  // 16 x 64
  DCMP_W5_OFF = 1750528,  // 512 x 64  (48 padded to 64, pad = 0)
  W_TOTAL     = 1783296,
};

// =============================== weight prep ===============================
__global__ void prep_kernel(
    const float* __restrict__ ew0, const float* __restrict__ ew1, const float* __restrict__ ew2,
    const float* __restrict__ dw0, const float* __restrict__ dw1, const float* __restrict__ dw2,
    const float* __restrict__ cw0, const float* __restrict__ cw1, const float* __restrict__ cw2,
    const float* __restrict__ cw3, const float* __restrict__ cw4, const float* __restrict__ cw5,
    const float* __restrict__ xw0, const float* __restrict__ xw1, const float* __restrict__ xw2,
    const float* __restrict__ xw3, const float* __restrict__ xw4, const float* __restrict__ xw5,
    __bf16* __restrict__ wb)
{
  for (int i = blockIdx.x * blockDim.x + threadIdx.x; i < W_TOTAL; i += gridDim.x * blockDim.x) {
    float v;
    if      (i < ENC_W1_OFF)  v = ew0[i - ENC_W0_OFF];
    else if (i < ENC_W2_OFF)  v = ew1[i - ENC_W1_OFF];
    else if (i < DEC_W0_OFF)  v = ew2[i - ENC_W2_OFF];
    else if (i < DEC_W1_OFF)  v = dw0[i - DEC_W0_OFF];
    else if (i < DEC_W2_OFF)  v = dw1[i - DEC_W1_OFF];
    else if (i < COMP_W0_OFF) v = dw2[i - DEC_W2_OFF];
    else if (i < COMP_W1_OFF) { int t = i - COMP_W0_OFF; int o = t >> 9, c = t & 511;
                                v = cw0[o * 1024 + c] + cw0[o * 1024 + 512 + c]; }
    else if (i < COMP_W2_OFF) v = cw1[i - COMP_W1_OFF];
    else if (i < COMP_W3_OFF) v = cw2[i - COMP_W2_OFF];
    else if (i < COMP_W4_OFF) v = cw3[i - COMP_W3_OFF];
    else if (i < COMP_W5_OFF) v = cw4[i - COMP_W4_OFF];
    else if (i < DCMP_W0_OFF) { int t = i - COMP_W5_OFF; int o = t / 544, c = t % 544;
                                v = (c < 528) ? cw5[o * 528 + c] : 0.0f; }
    else if (i < DCMP_W1_OFF) { int t = i - DCMP_W0_OFF; int o = t >> 5, c = t & 31;
                                v = xw0[o * 64 + c] + xw0[o * 64 + 32 + c]; }
    else if (i < DCMP_W2_OFF) v = xw1[i - DCMP_W1_OFF];
    else if (i < DCMP_W3_OFF) v = xw2[i - DCMP_W2_OFF];
    else if (i < DCMP_W4_OFF) v = xw3[i - DCMP_W3_OFF];
    else if (i < DCMP_W5_OFF) v = xw4[i - DCMP_W4_OFF];
    else                      { int t = i - DCMP_W5_OFF; int o = t >> 6, c = t & 63;
                                v = (c < 48) ? xw5[o * 48 + c] : 0.0f; }
    wb[i] = (__bf16)v;
  }
}

struct BiasPack {
  const float *eb0, *eb1, *eb2, *db0, *db1, *db2;
  const float *cb0, *cb1, *cb2, *cb3, *cb4, *cb5;
  const float *xb0, *xb1, *xb2, *xb3, *xb4, *xb5;
};

// ====================== fully fused pipeline kernel ========================
// One block = 64 batch rows through enc(16) -> comp -> decomp -> dec(16).
// 512 threads = 8 waves. LDS ~123 KB -> 1 block/CU; grid 512 = 2 rounds/CU.
// LDS map (bytes):
//   [0, 66560)          zs[64][520]   z_stack, later z_stack_hat
//   [66560, 117760)     region B, phase-aliased:
//       enc:  xc[2][64][40] (10240) | h1e[64][136] (17408) | h2e[64][72] (9216)
//       comp: sA[64][264] (33792)   | sB[64][136] (17408)
//       dec:  h1d[64][72] (9216)    | h2d[64][136] (17408)
//   [117760, 122880)    zsm[64][40]  compressed z (cols 0..31 used)
__global__ __launch_bounds__(512, 2)
void fused_kernel(const float* __restrict__ x, const __bf16* __restrict__ wb,
                  BiasPack bp, float* __restrict__ out)
{
  __shared__ __align__(16) char smem[122880];
  __bf16* zs  = (__bf16*)(smem);
  __bf16* xc  = (__bf16*)(smem + 66560);
  __bf16* h1e = (__bf16*)(smem + 66560 + 10240);
  __bf16* h2e = (__bf16*)(smem + 66560 + 27648);
  __bf16* sA  = (__bf16*)(smem + 66560);
  __bf16* sB  = (__bf16*)(smem + 66560 + 33792);
  __bf16* h1d = (__bf16*)(smem + 66560);
  __bf16* h2d = (__bf16*)(smem + 66560 + 9216);
  __bf16* zsm = (__bf16*)(smem + 117760);

  const int tid  = threadIdx.x;
  const int wv   = tid >> 6, lane = tid & 63;
  const int l15  = lane & 15, hi8 = (lane >> 4) * 8, rloc = (lane >> 4) * 4;
  const int m0   = blockIdx.x * 64;

  // x streaming: thread owns (row = tid>>3, 4 cols at (tid&7)*4) per 32-col chunk
  const int xrow = tid >> 3, xc4 = (tid & 7) * 4;
  const float* xbase = x + (size_t)(m0 + xrow) * 4096 + xc4;

  float4 xr[8];
  #pragma unroll
  for (int i = 0; i < 8; ++i) xr[i] = *(const float4*)(xbase + i * 32);

  // ============================ ENCODER ============================
  for (int e = 0; e < 16; ++e) {
    // L0: N=128, K=256 streamed in 8 chunks. Wave wv owns cols [wv*16, wv*16+16).
    const __bf16* W0 = wb + ENC_W0_OFF + e * 32768;
    bf16x8 bw0[8];
    #pragma unroll
    for (int i = 0; i < 8; ++i)
      bw0[i] = *(const bf16x8*)(W0 + (size_t)(wv * 16 + l15) * 256 + i * 32 + hi8);
    f32x4 acc0[4];
    {
      float bv = bp.eb0[e * 128 + wv * 16 + l15];
      f32x4 b4 = {bv, bv, bv, bv};
      #pragma unroll
      for (int rf = 0; rf < 4; ++rf) acc0[rf] = b4;
    }
    {  // chunk 0 -> LDS
      bf16x4 o = {(__bf16)xr[0].x, (__bf16)xr[0].y, (__bf16)xr[0].z, (__bf16)xr[0].w};
      *(bf16x4*)&xc[0 * 2560 + xrow * 40 + xc4] = o;
    }
    __syncthreads();
    #pragma unroll
    for (int i = 0; i < 8; ++i) {
      if (i < 7) {  // stage chunk i+1 into the other half
        bf16x4 o = {(__bf16)xr[i + 1].x, (__bf16)xr[i + 1].y, (__bf16)xr[i + 1].z, (__bf16)xr[i + 1].w};
        *(bf16x4*)&xc[((i + 1) & 1) * 2560 + xrow * 40 + xc4] = o;
      }
      #pragma unroll
      for (int rf = 0; rf < 4; ++rf) {
        bf16x8 a = *(const bf16x8*)&xc[(i & 1) * 2560 + (rf * 16 + l15) * 40 + hi8];
        acc0[rf] = MFMA16(a, bw0[i], acc0[rf]);
      }
      __syncthreads();
    }
    // prefetch next e's x while computing L0 epilogue / L1 / L2
    if (e < 15) {
      #pragma unroll
      for (int i = 0; i < 8; ++i) xr[i] = *(const float4*)(xbase + (e + 1) * 256 + i * 32);
    }
    #pragma unroll
    for (int rf = 0; rf < 4; ++rf)
      #pragma unroll
      for (int r = 0; r < 4; ++r)
        h1e[(rf * 16 + rloc + r) * 136 + wv * 16 + l15] = (__bf16)sigm(acc0[rf][r]);
    __syncthreads();

    // L1: N=64, K=128. wave -> (col tile wc1 = wv&3, row half wr1 = wv>>2)
    {
      const __bf16* W1 = wb + ENC_W1_OFF + e * 8192;
      const int wc1 = wv & 3, wr1 = wv >> 2;
      f32x4 acc1[2];
      float bv = bp.eb1[e * 64 + wc1 * 16 + l15];
      f32x4 b4 = {bv, bv, bv, bv};
      acc1[0] = b4; acc1[1] = b4;
      #pragma unroll
      for (int ks = 0; ks < 4; ++ks) {
        bf16x8 b = *(const bf16x8*)(W1 + (size_t)(wc1 * 16 + l15) * 128 + ks * 32 + hi8);
        #pragma unroll
        for (int rf = 0; rf < 2; ++rf) {
          bf16x8 a = *(const bf16x8*)&h1e[(wr1 * 32 + rf * 16 + l15) * 136 + ks * 32 + hi8];
          acc1[rf] = MFMA16(a, b, acc1[rf]);
        }
      }
      #pragma unroll
      for (int rf = 0; rf < 2; ++rf)
        #pragma unroll
        for (int r = 0; r < 4; ++r)
          h2e[(wr1 * 32 + rf * 16 + rloc + r) * 72 + wc1 * 16 + l15] = (__bf16)sigm(acc1[rf][r]);
    }
    __syncthreads();

    // L2: N=32, K=64, no sigmoid. wave -> (wc2 = wv&1, row quarter wr2 = wv>>1)
    {
      const __bf16* W2 = wb + ENC_W2_OFF + e * 2048;
      const int wc2 = wv & 1, wr2 = wv >> 1;
      float bv = bp.eb2[e * 32 + wc2 * 16 + l15];
      f32x4 acc2 = {bv, bv, bv, bv};
      #pragma unroll
      for (int ks = 0; ks < 2; ++ks) {
        bf16x8 a = *(const bf16x8*)&h2e[(wr2 * 16 + l15) * 72 + ks * 32 + hi8];
        bf16x8 b = *(const bf16x8*)(W2 + (size_t)(wc2 * 16 + l15) * 64 + ks * 32 + hi8);
        acc2 = MFMA16(a, b, acc2);
      }
      #pragma unroll
      for (int r = 0; r < 4; ++r)
        zs[(wr2 * 16 + rloc + r) * 520 + e * 32 + wc2 * 16 + l15] = (__bf16)acc2[r];
    }
    __syncthreads();
  }

  // ============================ COMPRESSOR ============================
  {
    const float* cbias[6] = {bp.cb0, bp.cb1, bp.cb2, bp.cb3, bp.cb4, bp.cb5};
    const int NF[6]   = {16, 8, 4, 2, 1, 2};
    const int KS2[6]  = {0, 8, 4, 2, 1, 1};
    const int WOFF[6] = {COMP_W0_OFF, COMP_W1_OFF, COMP_W2_OFF, COMP_W3_OFF, COMP_W4_OFF, COMP_W5_OFF};
    const int KT[6]   = {512, 768, 640, 576, 544, 544};
    #pragma unroll
    for (int L = 0; L < 6; ++L) {
      const int nf = NF[L];
      const __bf16* W = wb + WOFF[L];
      const int kt = KT[L];
      f32x4 acc[4][2];
      #pragma unroll
      for (int j = 0; j < 2; ++j) {
        int c = wv + 8 * j;
        if (c < nf) {
          float bv = cbias[L][c * 16 + l15];
          f32x4 b4 = {bv, bv, bv, bv};
          #pragma unroll
          for (int rf = 0; rf < 4; ++rf) acc[rf][j] = b4;
        }
      }
      for (int ks = 0; ks < 16; ++ks) {  // z part, K=512
        bf16x8 a[4];
        #pragma unroll
        for (int rf = 0; rf < 4; ++rf)
          a[rf] = *(const bf16x8*)&zs[(rf * 16 + l15) * 520 + ks * 32 + hi8];
        #pragma unroll
        for (int j = 0; j < 2; ++j) {
          int c = wv + 8 * j;
          if (c < nf) {
            bf16x8 b = *(const bf16x8*)(W + (size_t)(c * 16 + l15) * kt + ks * 32 + hi8);
            #pragma unroll
            for (int rf = 0; rf < 4; ++rf) acc[rf][j] = MFMA16(a[rf], b, acc[rf][j]);
          }
        }
      }
      if (L > 0) {  // s part
        __bf16* sp = (L & 1) ? sA : sB;
        const int pld = (L & 1) ? 264 : 136;
        for (int ks = 0; ks < KS2[L]; ++ks) {
          bf16x8 a[4];
          #pragma unroll
          for (int rf = 0; rf < 4; ++rf)
            a[rf] = *(const bf16x8*)&sp[(rf * 16 + l15) * pld + ks * 32 + hi8];
          #pragma unroll
          for (int j = 0; j < 2; ++j) {
            int c = wv + 8 * j;
            if (c < nf) {
              bf16x8 b = *(const bf16x8*)(W + (size_t)(c * 16 + l15) * kt + 512 + ks * 32 + hi8);
              #pragma unroll
              for (int rf = 0; rf < 4; ++rf) acc[rf][j] = MFMA16(a[rf], b, acc[rf][j]);
            }
          }
        }
      }
      if (L < 5) {
        __bf16* so = (L & 1) ? sB : sA;
        const int old_ = (L & 1) ? 136 : 264;
        #pragma unroll
        for (int j = 0; j < 2; ++j) {
          int c = wv + 8 * j;
          if (c < nf) {
            #pragma unroll
            for (int rf = 0; rf < 4; ++rf)
              #pragma unroll
              for (int r = 0; r < 4; ++r)
                so[(rf * 16 + rloc + r) * old_ + c * 16 + l15] = (__bf16)sigm(acc[rf][j][r]);
          }
        }
        if (L == 4) {  // zero-pad s4 cols 16..31 (match zero weight pad)
          for (int i = tid; i < 64 * 16; i += 512) sA[(i >> 4) * 264 + 16 + (i & 15)] = (__bf16)0.0f;
        }
      } else {  // final: z (64x32) -> zsm, linear
        #pragma unroll
        for (int j = 0; j < 2; ++j) {
          int c = wv + 8 * j;
          if (c < nf) {
            #pragma unroll
            for (int rf = 0; rf < 4; ++rf)
              #pragma unroll
              for (int r = 0; r < 4; ++r)
                zsm[(rf * 16 + rloc + r) * 40 + c * 16 + l15] = (__bf16)acc[rf][j][r];
          }
        }
      }
      __syncthreads();
    }
  }

  // ============================ DECOMPRESSOR ============================
  {
    const float* dbias[5] = {bp.xb0, bp.xb1, bp.xb2, bp.xb3, bp.xb4};
    const int NF[5]   = {16, 8, 4, 2, 1};
    const int KS2[5]  = {0, 8, 4, 2, 1};
    const int WOFF[5] = {DCMP_W0_OFF, DCMP_W1_OFF, DCMP_W2_OFF, DCMP_W3_OFF, DCMP_W4_OFF};
    const int KT[5]   = {32, 288, 160, 96, 64};
    #pragma unroll
    for (int L = 0; L < 5; ++L) {
      const int nf = NF[L];
      const __bf16* W = wb + WOFF[L];
      const int kt = KT[L];
      f32x4 acc[4][2];
      #pragma unroll
      for (int j = 0; j < 2; ++j) {
        int c = wv + 8 * j;
        if (c < nf) {
          float bv = dbias[L][c * 16 + l15];
          f32x4 b4 = {bv, bv, bv, bv};
          #pragma unroll
          for (int rf = 0; rf < 4; ++rf) acc[rf][j] = b4;
        }
      }
      {  // z part, K=32
        bf16x8 a[4];
        #pragma unroll
        for (int rf = 0; rf < 4; ++rf)
          a[rf] = *(const bf16x8*)&zsm[(rf * 16 + l15) * 40 + hi8];
        #pragma unroll
        for (int j = 0; j < 2; ++j) {
          int c = wv + 8 * j;
          if (c < nf) {
            bf16x8 b = *(const bf16x8*)(W + (size_t)(c * 16 + l15) * kt + hi8);
            #pragma unroll
            for (int rf = 0; rf < 4; ++rf) acc[rf][j] = MFMA16(a[rf], b, acc[rf][j]);
          }
        }
      }
      if (L > 0) {
        __bf16* sp = (L & 1) ? sA : sB;
        const int pld = (L & 1) ? 264 : 136;
        for (int ks = 0; ks < KS2[L]; ++ks) {
          bf16x8 a[4];
          #pragma unroll
          for (int rf = 0; rf < 4; ++rf)
            a[rf] = *(const bf16x8*)&sp[(rf * 16 + l15) * pld + ks * 32 + hi8];
          #pragma unroll
          for (int j = 0; j < 2; ++j) {
            int c = wv + 8 * j;
            if (c < nf) {
              bf16x8 b = *(const bf16x8*)(W + (size_t)(c * 16 + l15) * kt + 32 + ks * 32 + hi8);
              #pragma unroll
              for (int rf = 0; rf < 4; ++rf) acc[rf][j] = MFMA16(a[rf], b, acc[rf][j]);
            }
          }
        }
      }
      {
        __bf16* so = (L & 1) ? sB : sA;
        const int old_ = (L & 1) ? 136 : 264;
        #pragma unroll
        for (int j = 0; j < 2; ++j) {
          int c = wv + 8 * j;
          if (c < nf) {
            #pragma unroll
            for (int rf = 0; rf < 4; ++rf)
              #pragma unroll
              for (int r = 0; r < 4; ++r)
                so[(rf * 16 + rloc + r) * old_ + c * 16 + l15] = (__bf16)sigm(acc[rf][j][r]);
          }
        }
        if (L == 4) {
          for (int i = tid; i < 64 * 16; i += 512) sA[(i >> 4) * 264 + 16 + (i & 15)] = (__bf16)0.0f;
        }
      }
      __syncthreads();
    }
    // final layer: N=512, KT=64 (z cols 0..31, s4 cols 32..47, zero pad) -> zs (z_stack_hat)
    {
      const __bf16* W = wb + DCMP_W5_OFF;
      f32x4 acc[4][4];
      #pragma unroll
      for (int j = 0; j < 4; ++j) {
        int c = wv + 8 * j;
        float bv = bp.xb5[c * 16 + l15];
        f32x4 b4 = {bv, bv, bv, bv};
        #pragma unroll
        for (int rf = 0; rf < 4; ++rf) acc[rf][j] = b4;
      }
      bf16x8 az[4], as[4];
      #pragma unroll
      for (int rf = 0; rf < 4; ++rf) {
        az[rf] = *(const bf16x8*)&zsm[(rf * 16 + l15) * 40 + hi8];
        as[rf] = *(const bf16x8*)&sA[(rf * 16 + l15) * 264 + hi8];
      }
      #pragma unroll
      for (int j = 0; j < 4; ++j) {
        int c = wv + 8 * j;
        bf16x8 bz = *(const bf16x8*)(W + (size_t)(c * 16 + l15) * 64 + hi8);
        bf16x8 bs = *(const bf16x8*)(W + (size_t)(c * 16 + l15) * 64 + 32 + hi8);
        #pragma unroll
        for (int rf = 0; rf < 4; ++rf) {
          acc[rf][j] = MFMA16(az[rf], bz, acc[rf][j]);
          acc[rf][j] = MFMA16(as[rf], bs, acc[rf][j]);
        }
      }
      __syncthreads();  // zs z_stack reads (comp) fully done; also sA reads done
      #pragma unroll
      for (int j = 0; j < 4; ++j) {
        int c = wv + 8 * j;
        #pragma unroll
        for (int rf = 0; rf < 4; ++rf)
          #pragma unroll
          for (int r = 0; r < 4; ++r)
            zs[(rf * 16 + rloc + r) * 520 + c * 16 + l15] = (__bf16)acc[rf][j][r];
      }
    }
    __syncthreads();
  }

  // ============================ DECODER ============================
  for (int e = 0; e < 16; ++e) {
    // L0: N=64, K=32. wave -> (wc1 = wv&3, row half wr1 = wv>>2)
    {
      const __bf16* W = wb + DEC_W0_OFF + e * 2048;
      const int wc1 = wv & 3, wr1 = wv >> 2;
      f32x4 acc[2];
      float bv = bp.db0[e * 64 + wc1 * 16 + l15];
      f32x4 b4 = {bv, bv, bv, bv};
      acc[0] = b4; acc[1] = b4;
      bf16x8 b = *(const bf16x8*)(W + (size_t)(wc1 * 16 + l15) * 32 + hi8);
      #pragma unroll
      for (int rf = 0; rf < 2; ++rf) {
        bf16x8 a = *(const bf16x8*)&zs[(wr1 * 32 + rf * 16 + l15) * 520 + e * 32 + hi8];
        acc[rf] = MFMA16(a, b, acc[rf]);
      }
      #pragma unroll
      for (int rf = 0; rf < 2; ++rf)
        #pragma unroll
        for (int r = 0; r < 4; ++r)
          h1d[(wr1 * 32 + rf * 16 + rloc + r) * 72 + wc1 * 16 + l15] = (__bf16)sigm(acc[rf][r]);
    }
    __syncthreads();

    // L1: N=128, K=64. wave wv -> cols [wv*16, wv*16+16), all 64 rows
    {
      const __bf16* W = wb + DEC_W1_OFF + e * 8192;
      f32x4 acc[4];
      float bv = bp.db1[e * 128 + wv * 16 + l15];
      f32x4 b4 = {bv, bv, bv, bv};
      #pragma unroll
      for (int rf = 0; rf < 4; ++rf) acc[rf] = b4;
      #pragma unroll
      for (int ks = 0; ks < 2; ++ks) {
        bf16x8 b = *(const bf16x8*)(W + (size_t)(wv * 16 + l15) * 64 + ks * 32 + hi8);
        #pragma unroll
        for (int rf = 0; rf < 4; ++rf) {
          bf16x8 a = *(const bf16x8*)&h1d[(rf * 16 + l15) * 72 + ks * 32 + hi8];
          acc[rf] = MFMA16(a, b, acc[rf]);
        }
      }
      #pragma unroll
      for (int rf = 0; rf < 4; ++rf)
        #pragma unroll
        for (int r = 0; r < 4; ++r)
          h2d[(rf * 16 + rloc + r) * 136 + wv * 16 + l15] = (__bf16)sigm(acc[rf][r]);
    }
    __syncthreads();

    // L2: N=256, K=128, no sigmoid, fp32 out. wave -> cols [wv*32, wv*32+32)
    {
      const __bf16* W = wb + DEC_W2_OFF + e * 32768;
      f32x4 acc[4][2];
      #pragma unroll
      for (int cf = 0; cf < 2; ++cf) {
        float bv = bp.db2[e * 256 + wv * 32 + cf * 16 + l15];
        f32x4 b4 = {bv, bv, bv, bv};
        #pragma unroll
        for (int rf = 0; rf < 4; ++rf) acc[rf][cf] = b4;
      }
      #pragma unroll
      for (int ks = 0; ks < 4; ++ks) {
        bf16x8 b0 = *(const bf16x8*)(W + (size_t)(wv * 32 + l15) * 128 + ks * 32 + hi8);
        bf16x8 b1 = *(const bf16x8*)(W + (size_t)(wv * 32 + 16 + l15) * 128 + ks * 32 + hi8);
        #pragma unroll
        for (int rf = 0; rf < 4; ++rf) {
          bf16x8 a = *(const bf16x8*)&h2d[(rf * 16 + l15) * 136 + ks * 32 + hi8];
          acc[rf][0] = MFMA16(a, b0, acc[rf][0]);
          acc[rf][1] = MFMA16(a, b1, acc[rf][1]);
        }
      }
      #pragma unroll
      for (int cf = 0; cf < 2; ++cf)
        #pragma unroll
        for (int rf = 0; rf < 4; ++rf)
          #pragma unroll
          for (int r = 0; r < 4; ++r)
            out[(size_t)(m0 + rf * 16 + rloc + r) * 4096 + e * 256 + wv * 32 + cf * 16 + l15] =
                acc[rf][cf][r];
    }
    __syncthreads();
  }
}

// =============================== launcher ==================================
extern "C" void kernel_launch(void* const* d_in, const int* in_sizes, int n_in,
                              void* d_out, int out_size, void* d_ws, size_t ws_size,
                              hipStream_t stream) {
  (void)in_sizes; (void)n_in; (void)out_size; (void)ws_size;
  const float* x   = (const float*)d_in[0];
  const float* ew0 = (const float*)d_in[1];  const float* eb0 = (const float*)d_in[2];
  const float* ew1 = (const float*)d_in[3];  const float* eb1 = (const float*)d_in[4];
  const float* ew2 = (const float*)d_in[5];  const float* eb2 = (const float*)d_in[6];
  const float* dw0 = (const float*)d_in[7];  const float* db0 = (const float*)d_in[8];
  const float* dw1 = (const float*)d_in[9];  const float* db1 = (const float*)d_in[10];
  const float* dw2 = (const float*)d_in[11]; const float* db2 = (const float*)d_in[12];
  const float* cw[6]; const float* cb[6];
  for (int i = 0; i < 6; ++i) { cw[i] = (const float*)d_in[13 + 2 * i]; cb[i] = (const float*)d_in[14 + 2 * i]; }
  const float* xw[6]; const float* xb[6];
  for (int i = 0; i < 6; ++i) { xw[i] = (const float*)d_in[25 + 2 * i]; xb[i] = (const float*)d_in[26 + 2 * i]; }

  __bf16* wbuf = (__bf16*)d_ws;
  float* out = (float*)d_out;

  prep_kernel<<<1024, 256, 0, stream>>>(ew0, ew1, ew2, dw0, dw1, dw2,
                                        cw[0], cw[1], cw[2], cw[3], cw[4], cw[5],
                                        xw[0], xw[1], xw[2], xw[3], xw[4], xw[5], wbuf);
  BiasPack bp = {eb0, eb1, eb2, db0, db1, db2,
                 cb[0], cb[1], cb[2], cb[3], cb[4], cb[5],
                 xb[0], xb[1], xb[2], xb[3], xb[4], xb[5]};
  fused_kernel<<<512, 512, 0, stream>>>(x, wbuf, bp, out);
}

// Round 4
// 600.531 us; speedup vs baseline: 1.2385x; 1.2385x over previous
//
#include <hip/hip_runtime.h>

typedef __bf16 bf16x8 __attribute__((ext_vector_type(8)));
typedef __bf16 bf16x4 __attribute__((ext_vector_type(4)));
typedef float  f32x4  __attribute__((ext_vector_type(4)));

#define MFMA16(a, b, c) __builtin_amdgcn_mfma_f32_16x16x32_bf16((a), (b), (c), 0, 0, 0)

__device__ __forceinline__ float sigm(float x) { return 1.0f / (1.0f + __expf(-x)); }

// ---- packed bf16 weight layout (element offsets inside d_ws) ----
enum : int {
  ENC_W0_OFF  = 0,        // 16 x 128 x 256
  ENC_W1_OFF  = 524288,   // 16 x 64 x 128
  ENC_W2_OFF  = 655360,   // 16 x 32 x 64
  DEC_W0_OFF  = 688128,   // 16 x 64 x 32
  DEC_W1_OFF  = 720896,   // 16 x 128 x 64
  DEC_W2_OFF  = 851968,   // 16 x 256 x 128
  COMP_W0_OFF = 1376256,  // 256 x 512  (folded [z,z])
  COMP_W1_OFF = 1507328,  // 128 x 768
  COMP_W2_OFF = 1605632,  // 64 x 640
  COMP_W3_OFF = 1646592,  // 32 x 576
  COMP_W4_OFF = 1665024,  // 16 x 544
  COMP_W5_OFF = 1673728,  // 32 x 544  (528 padded to 544, pad = 0)
  DCMP_W0_OFF = 1691136,  // 256 x 32  (folded)
  DCMP_W1_OFF = 1699328,  // 128 x 288
  DCMP_W2_OFF = 1736192,  // 64 x 160
  DCMP_W3_OFF = 1746432,  // 32 x 96
  DCMP_W4_OFF = 1749504,  // 16 x 64
  DCMP_W5_OFF = 1750528,  // 512 x 64  (48 padded to 64, pad = 0)
  W_TOTAL     = 1783296,
};

#define ZS_BYTES_OFF (4u * 1024u * 1024u)  // z_stack, overwritten in-place by z_stack_hat

// =============================== weight prep ===============================
__global__ void prep_kernel(
    const float* __restrict__ ew0, const float* __restrict__ ew1, const float* __restrict__ ew2,
    const float* __restrict__ dw0, const float* __restrict__ dw1, const float* __restrict__ dw2,
    const float* __restrict__ cw0, const float* __restrict__ cw1, const float* __restrict__ cw2,
    const float* __restrict__ cw3, const float* __restrict__ cw4, const float* __restrict__ cw5,
    const float* __restrict__ xw0, const float* __restrict__ xw1, const float* __restrict__ xw2,
    const float* __restrict__ xw3, const float* __restrict__ xw4, const float* __restrict__ xw5,
    __bf16* __restrict__ wb)
{
  for (int i = blockIdx.x * blockDim.x + threadIdx.x; i < W_TOTAL; i += gridDim.x * blockDim.x) {
    float v;
    if      (i < ENC_W1_OFF)  v = ew0[i - ENC_W0_OFF];
    else if (i < ENC_W2_OFF)  v = ew1[i - ENC_W1_OFF];
    else if (i < DEC_W0_OFF)  v = ew2[i - ENC_W2_OFF];
    else if (i < DEC_W1_OFF)  v = dw0[i - DEC_W0_OFF];
    else if (i < DEC_W2_OFF)  v = dw1[i - DEC_W1_OFF];
    else if (i < COMP_W0_OFF) v = dw2[i - DEC_W2_OFF];
    else if (i < COMP_W1_OFF) { int t = i - COMP_W0_OFF; int o = t >> 9, c = t & 511;
                                v = cw0[o * 1024 + c] + cw0[o * 1024 + 512 + c]; }
    else if (i < COMP_W2_OFF) v = cw1[i - COMP_W1_OFF];
    else if (i < COMP_W3_OFF) v = cw2[i - COMP_W2_OFF];
    else if (i < COMP_W4_OFF) v = cw3[i - COMP_W3_OFF];
    else if (i < COMP_W5_OFF) v = cw4[i - COMP_W4_OFF];
    else if (i < DCMP_W0_OFF) { int t = i - COMP_W5_OFF; int o = t / 544, c = t % 544;
                                v = (c < 528) ? cw5[o * 528 + c] : 0.0f; }
    else if (i < DCMP_W1_OFF) { int t = i - DCMP_W0_OFF; int o = t >> 5, c = t & 31;
                                v = xw0[o * 64 + c] + xw0[o * 64 + 32 + c]; }
    else if (i < DCMP_W2_OFF) v = xw1[i - DCMP_W1_OFF];
    else if (i < DCMP_W3_OFF) v = xw2[i - DCMP_W2_OFF];
    else if (i < DCMP_W4_OFF) v = xw3[i - DCMP_W3_OFF];
    else if (i < DCMP_W5_OFF) v = xw4[i - DCMP_W4_OFF];
    else                      { int t = i - DCMP_W5_OFF; int o = t >> 6, c = t & 63;
                                v = (c < 48) ? xw5[o * 48 + c] : 0.0f; }
    wb[i] = (__bf16)v;
  }
}

// =============================== encoder ===================================
// Block = 64 rows, 8 waves, loops over all 16 encoders. x streamed as 32
// half-slabs (64x128 fp32) with 2-deep register prefetch. ~60 KB LDS -> 2/CU.
__global__ __launch_bounds__(512, 4)
void enc_kernel(const float* __restrict__ x, const __bf16* __restrict__ wb,
                const float* __restrict__ b0, const float* __restrict__ b1,
                const float* __restrict__ b2, __bf16* __restrict__ zout)
{
  __shared__ __bf16 xs[2][64][136];
  __shared__ __bf16 h1[64][136];
  __shared__ __bf16 h2[64][72];
  const int tid = threadIdx.x;
  const int wv = tid >> 6, lane = tid & 63;
  const int l15 = lane & 15, hi8 = (lane >> 4) * 8, rloc = (lane >> 4) * 4;
  const int m0 = blockIdx.x * 64;
  const int xrow = tid >> 3, xck = tid & 7;
  const float* xbase = x + (size_t)(m0 + xrow) * 4096 + xck * 4;
  const int wc = wv & 3, wr = wv >> 2;

  float4 rg[2][4];
  #pragma unroll
  for (int j = 0; j < 4; ++j) rg[0][j] = *(const float4*)(xbase + 0 * 128 + j * 32);
  #pragma unroll
  for (int j = 0; j < 4; ++j) rg[1][j] = *(const float4*)(xbase + 1 * 128 + j * 32);
  #pragma unroll
  for (int j = 0; j < 4; ++j) {
    float4 v = rg[0][j];
    bf16x4 o = {(__bf16)v.x, (__bf16)v.y, (__bf16)v.z, (__bf16)v.w};
    *(bf16x4*)&xs[0][xrow][xck * 4 + j * 32] = o;
  }
  __syncthreads();

  f32x4 acc0[2][2];
  #pragma unroll 2   // makes h&1 compile-time -> rg[] statically indexed
  for (int h = 0; h < 32; ++h) {
    const int e = h >> 1, q = h & 1, p = h & 1;
    if (h < 31) {  // stage slab h+1 (held in rg[(h+1)&1]) into LDS buf (h+1)&1
      #pragma unroll
      for (int j = 0; j < 4; ++j) {
        float4 v = rg[(h + 1) & 1][j];
        bf16x4 o = {(__bf16)v.x, (__bf16)v.y, (__bf16)v.z, (__bf16)v.w};
        *(bf16x4*)&xs[(h + 1) & 1][xrow][xck * 4 + j * 32] = o;
      }
    }
    if (h < 30) {  // issue loads for slab h+2 into just-freed reg set
      #pragma unroll
      for (int j = 0; j < 4; ++j)
        rg[h & 1][j] = *(const float4*)(xbase + (size_t)(h + 2) * 128 + j * 32);
    }
    if (q == 0) {
      #pragma unroll
      for (int cf = 0; cf < 2; ++cf) {
        float bv = b0[e * 128 + wc * 32 + cf * 16 + l15];
        f32x4 b4 = {bv, bv, bv, bv};
        acc0[0][cf] = b4; acc0[1][cf] = b4;
      }
    }
    // L0 partial: 4 k-steps from xs[p], global k = q*128 + ks*32
    const __bf16* W0 = wb + ENC_W0_OFF + e * 32768;
    #pragma unroll
    for (int ks = 0; ks < 4; ++ks) {
      bf16x8 a[2], bb[2];
      #pragma unroll
      for (int rf = 0; rf < 2; ++rf)
        a[rf] = *(const bf16x8*)&xs[p][wr * 32 + rf * 16 + l15][ks * 32 + hi8];
      #pragma unroll
      for (int cf = 0; cf < 2; ++cf)
        bb[cf] = *(const bf16x8*)(W0 + (size_t)(wc * 32 + cf * 16 + l15) * 256 + q * 128 + ks * 32 + hi8);
      #pragma unroll
      for (int rf = 0; rf < 2; ++rf)
        #pragma unroll
        for (int cf = 0; cf < 2; ++cf)
          acc0[rf][cf] = MFMA16(a[rf], bb[cf], acc0[rf][cf]);
    }
    if (q == 0) { __syncthreads(); continue; }
    // ---- end of e's K: L0 epilogue ----
    #pragma unroll
    for (int rf = 0; rf < 2; ++rf)
      #pragma unroll
      for (int cf = 0; cf < 2; ++cf)
        #pragma unroll
        for (int r = 0; r < 4; ++r)
          h1[wr * 32 + rf * 16 + rloc + r][wc * 32 + cf * 16 + l15] = (__bf16)sigm(acc0[rf][cf][r]);
    __syncthreads();
    // L1: N=64, K=128. wave (wc cols, wr row-half)
    {
      const __bf16* W1 = wb + ENC_W1_OFF + e * 8192;
      f32x4 acc1[2];
      float bv = b1[e * 64 + wc * 16 + l15];
      f32x4 b4 = {bv, bv, bv, bv};
      acc1[0] = b4; acc1[1] = b4;
      #pragma unroll
      for (int ks = 0; ks < 4; ++ks) {
        bf16x8 bb = *(const bf16x8*)(W1 + (size_t)(wc * 16 + l15) * 128 + ks * 32 + hi8);
        #pragma unroll
        for (int rf = 0; rf < 2; ++rf) {
          bf16x8 a = *(const bf16x8*)&h1[wr * 32 + rf * 16 + l15][ks * 32 + hi8];
          acc1[rf] = MFMA16(a, bb, acc1[rf]);
        }
      }
      #pragma unroll
      for (int rf = 0; rf < 2; ++rf)
        #pragma unroll
        for (int r = 0; r < 4; ++r)
          h2[wr * 32 + rf * 16 + rloc + r][wc * 16 + l15] = (__bf16)sigm(acc1[rf][r]);
    }
    __syncthreads();
    // L2: N=32, K=64, no sigmoid. wave (wc2 col, wq row-quarter)
    {
      const __bf16* W2 = wb + ENC_W2_OFF + e * 2048;
      const int wc2 = wv & 1, wq = wv >> 1;
      float bv = b2[e * 32 + wc2 * 16 + l15];
      f32x4 acc2 = {bv, bv, bv, bv};
      #pragma unroll
      for (int ks = 0; ks < 2; ++ks) {
        bf16x8 a = *(const bf16x8*)&h2[wq * 16 + l15][ks * 32 + hi8];
        bf16x8 bb = *(const bf16x8*)(W2 + (size_t)(wc2 * 16 + l15) * 64 + ks * 32 + hi8);
        acc2 = MFMA16(a, bb, acc2);
      }
      #pragma unroll
      for (int r = 0; r < 4; ++r)
        zout[(size_t)(m0 + wq * 16 + rloc + r) * 512 + e * 32 + wc2 * 16 + l15] = (__bf16)acc2[r];
    }
    // no trailing barrier needed: next even iter's sync precedes all hazards
  }
}

// ========================= middle (comp + decomp) ==========================
struct MidBias {
  const float *c0, *c1, *c2, *c3, *c4, *c5;
  const float *x0, *x1, *x2, *x3, *x4, *x5;
};

// One residual layer, all compile-time geometry. Wave mapping by NF:
// NF>=8: wave=col(s), all 64 rows. NF==4: (col, row-half). NF==2: (col,
// row-quarter). NF==1: waves 0-3 = row-quarters, waves 4-7 idle.
template<int NF, int KT, int ZKS, int ZLD, int SKS, int SLD, int DLD, bool SIG>
__device__ __forceinline__ void rlayer(const __bf16* __restrict__ W, const float* __restrict__ bias,
                                       const __bf16* __restrict__ zp, const __bf16* __restrict__ sp,
                                       __bf16* __restrict__ dst,
                                       int wv, int l15, int hi8, int rloc)
{
  constexpr int NJ = (NF >= 32) ? 4 : ((NF >= 16) ? 2 : 1);
  constexpr int NR = (NF >= 8) ? 4 : ((NF == 4) ? 2 : 1);
  int c0, row0;
  if constexpr (NF >= 8)       { c0 = wv;      row0 = 0; }
  else if constexpr (NF == 4)  { c0 = wv & 3;  row0 = (wv >> 2) * 32; }
  else if constexpr (NF == 2)  { c0 = wv & 1;  row0 = (wv >> 1) * 16; }
  else                         { if (wv >= 4) return; c0 = 0; row0 = wv * 16; }
  f32x4 acc[NR][NJ];
  #pragma unroll
  for (int j = 0; j < NJ; ++j) {
    float bv = bias[(c0 + 8 * j) * 16 + l15];
    f32x4 b4 = {bv, bv, bv, bv};
    #pragma unroll
    for (int rf = 0; rf < NR; ++rf) acc[rf][j] = b4;
  }
  #pragma unroll
  for (int ks = 0; ks < ZKS; ++ks) {
    bf16x8 a[NR];
    #pragma unroll
    for (int rf = 0; rf < NR; ++rf)
      a[rf] = *(const bf16x8*)&zp[(size_t)(row0 + rf * 16 + l15) * ZLD + ks * 32 + hi8];
    #pragma unroll
    for (int j = 0; j < NJ; ++j) {
      bf16x8 b = *(const bf16x8*)&W[(size_t)((c0 + 8 * j) * 16 + l15) * KT + ks * 32 + hi8];
      #pragma unroll
      for (int rf = 0; rf < NR; ++rf) acc[rf][j] = MFMA16(a[rf], b, acc[rf][j]);
    }
  }
  if constexpr (SKS > 0) {
    #pragma unroll
    for (int ks = 0; ks < SKS; ++ks) {
      bf16x8 a[NR];
      #pragma unroll
      for (int rf = 0; rf < NR; ++rf)
        a[rf] = *(const bf16x8*)&sp[(size_t)(row0 + rf * 16 + l15) * SLD + ks * 32 + hi8];
      #pragma unroll
      for (int j = 0; j < NJ; ++j) {
        bf16x8 b = *(const bf16x8*)&W[(size_t)((c0 + 8 * j) * 16 + l15) * KT + ZKS * 32 + ks * 32 + hi8];
        #pragma unroll
        for (int rf = 0; rf < NR; ++rf) acc[rf][j] = MFMA16(a[rf], b, acc[rf][j]);
      }
    }
  }
  #pragma unroll
  for (int j = 0; j < NJ; ++j)
    #pragma unroll
    for (int rf = 0; rf < NR; ++rf)
      #pragma unroll
      for (int r = 0; r < 4; ++r) {
        float v = acc[rf][j][r];
        dst[(size_t)(row0 + rf * 16 + rloc + r) * DLD + (c0 + 8 * j) * 16 + l15] =
            (__bf16)(SIG ? sigm(v) : v);
      }
}

__global__ __launch_bounds__(512, 2)
void mid_kernel(const __bf16* __restrict__ zin, const __bf16* __restrict__ wb,
                MidBias mb, __bf16* __restrict__ zhout)
{
  __shared__ __bf16 zs[64 * 520];
  __shared__ __bf16 sA[64 * 264];
  __shared__ __bf16 sB[64 * 136];
  __shared__ __bf16 zsm[64 * 40];
  const int tid = threadIdx.x;
  const int wv = tid >> 6, lane = tid & 63;
  const int l15 = lane & 15, hi8 = (lane >> 4) * 8, rloc = (lane >> 4) * 4;
  const int m0 = blockIdx.x * 64;

  #pragma unroll
  for (int i = 0; i < 8; ++i) {
    int idx = tid + i * 512;
    int r = idx >> 6, c8 = (idx & 63) * 8;
    *(bf16x8*)&zs[r * 520 + c8] = *(const bf16x8*)(zin + (size_t)(m0 + r) * 512 + c8);
  }
  __syncthreads();
  // ---- compressor ----
  rlayer<16, 512, 16, 520, 0,   0, 264, true >(wb + COMP_W0_OFF, mb.c0, zs, nullptr, sA, wv, l15, hi8, rloc); __syncthreads();
  rlayer< 8, 768, 16, 520, 8, 264, 136, true >(wb + COMP_W1_OFF, mb.c1, zs, sA, sB, wv, l15, hi8, rloc); __syncthreads();
  rlayer< 4, 640, 16, 520, 4, 136, 264, true >(wb + COMP_W2_OFF, mb.c2, zs, sB, sA, wv, l15, hi8, rloc); __syncthreads();
  rlayer< 2, 576, 16, 520, 2, 264, 136, true >(wb + COMP_W3_OFF, mb.c3, zs, sA, sB, wv, l15, hi8, rloc); __syncthreads();
  rlayer< 1, 544, 16, 520, 1, 136, 264, true >(wb + COMP_W4_OFF, mb.c4, zs, sB, sA, wv, l15, hi8, rloc);
  for (int i = tid; i < 64 * 16; i += 512) sA[(i >> 4) * 264 + 16 + (i & 15)] = (__bf16)0.0f;
  __syncthreads();
  rlayer< 2, 544, 16, 520, 1, 264,  40, false>(wb + COMP_W5_OFF, mb.c5, zs, sA, zsm, wv, l15, hi8, rloc); __syncthreads();
  // ---- decompressor ----
  rlayer<16,  32, 1, 40, 0,   0, 264, true >(wb + DCMP_W0_OFF, mb.x0, zsm, nullptr, sA, wv, l15, hi8, rloc); __syncthreads();
  rlayer< 8, 288, 1, 40, 8, 264, 136, true >(wb + DCMP_W1_OFF, mb.x1, zsm, sA, sB, wv, l15, hi8, rloc); __syncthreads();
  rlayer< 4, 160, 1, 40, 4, 136, 264, true >(wb + DCMP_W2_OFF, mb.x2, zsm, sB, sA, wv, l15, hi8, rloc); __syncthreads();
  rlayer< 2,  96, 1, 40, 2, 264, 136, true >(wb + DCMP_W3_OFF, mb.x3, zsm, sA, sB, wv, l15, hi8, rloc); __syncthreads();
  rlayer< 1,  64, 1, 40, 1, 136, 264, true >(wb + DCMP_W4_OFF, mb.x4, zsm, sB, sA, wv, l15, hi8, rloc);
  for (int i = tid; i < 64 * 16; i += 512) sA[(i >> 4) * 264 + 16 + (i & 15)] = (__bf16)0.0f;
  __syncthreads();
  // final 512-wide layer writes z_stack_hat straight to global (in-place over z_stack)
  rlayer<32,  64, 1, 40, 1, 264, 512, false>(wb + DCMP_W5_OFF, mb.x5, zsm, sA,
                                             zhout + (size_t)m0 * 512, wv, l15, hi8, rloc);
}

// =============================== decoder ===================================
// Block = 64 rows, 8 waves, loops e=0..15; z slice prefetched one e ahead.
// ~31 KB LDS -> 2/CU. Streams the 512 MB fp32 output.
__global__ __launch_bounds__(512, 4)
void dec_kernel(const __bf16* __restrict__ zh, const __bf16* __restrict__ wb,
                const float* __restrict__ b0, const float* __restrict__ b1,
                const float* __restrict__ b2, float* __restrict__ out)
{
  __shared__ __bf16 zsl[64][40];
  __shared__ __bf16 h1[64][72];
  __shared__ __bf16 h2[64][136];
  const int tid = threadIdx.x;
  const int wv = tid >> 6, lane = tid & 63;
  const int l15 = lane & 15, hi8 = (lane >> 4) * 8, rloc = (lane >> 4) * 4;
  const int m0 = blockIdx.x * 64;
  const int wc = wv & 3, wr = wv >> 2;
  const int zrow = tid >> 2, zc8 = (tid & 3) * 8;

  bf16x8 zr = {};
  if (tid < 256) {
    zr = *(const bf16x8*)(zh + (size_t)(m0 + zrow) * 512 + zc8);
    *(bf16x8*)&zsl[zrow][zc8] = zr;
  }
  __syncthreads();

  for (int e = 0; e < 16; ++e) {
    // L0: N=64, K=32. wave (wc col, wr row-half)
    {
      const __bf16* W0 = wb + DEC_W0_OFF + e * 2048;
      f32x4 a0[2];
      float bv = b0[e * 64 + wc * 16 + l15];
      f32x4 b4 = {bv, bv, bv, bv};
      a0[0] = b4; a0[1] = b4;
      bf16x8 bb = *(const bf16x8*)(W0 + (size_t)(wc * 16 + l15) * 32 + hi8);
      #pragma unroll
      for (int rf = 0; rf < 2; ++rf) {
        bf16x8 a = *(const bf16x8*)&zsl[wr * 32 + rf * 16 + l15][hi8];
        a0[rf] = MFMA16(a, bb, a0[rf]);
      }
      #pragma unroll
      for (int rf = 0; rf < 2; ++rf)
        #pragma unroll
        for (int r = 0; r < 4; ++r)
          h1[wr * 32 + rf * 16 + rloc + r][wc * 16 + l15] = (__bf16)sigm(a0[rf][r]);
    }
    if (e < 15 && tid < 256)  // prefetch next z slice
      zr = *(const bf16x8*)(zh + (size_t)(m0 + zrow) * 512 + (e + 1) * 32 + zc8);
    __syncthreads();
    // L1: N=128, K=64. wave col wv*16, all 64 rows
    {
      const __bf16* W1 = wb + DEC_W1_OFF + e * 8192;
      f32x4 a1[4];
      float bv = b1[e * 128 + wv * 16 + l15];
      f32x4 b4 = {bv, bv, bv, bv};
      #pragma unroll
      for (int rf = 0; rf < 4; ++rf) a1[rf] = b4;
      #pragma unroll
      for (int ks = 0; ks < 2; ++ks) {
        bf16x8 bb = *(const bf16x8*)(W1 + (size_t)(wv * 16 + l15) * 64 + ks * 32 + hi8);
        #pragma unroll
        for (int rf = 0; rf < 4; ++rf) {
          bf16x8 a = *(const bf16x8*)&h1[rf * 16 + l15][ks * 32 + hi8];
          a1[rf] = MFMA16(a, bb, a1[rf]);
        }
      }
      #pragma unroll
      for (int rf = 0; rf < 4; ++rf)
        #pragma unroll
        for (int r = 0; r < 4; ++r)
          h2[rf * 16 + rloc + r][wv * 16 + l15] = (__bf16)sigm(a1[rf][r]);
    }
    __syncthreads();
    // L2: N=256, K=128, fp32 out. wave cols [wv*32, wv*32+32)
    {
      const __bf16* W2 = wb + DEC_W2_OFF + e * 32768;
      f32x4 a2[4][2];
      #pragma unroll
      for (int cf = 0; cf < 2; ++cf) {
        float bv = b2[e * 256 + wv * 32 + cf * 16 + l15];
        f32x4 b4 = {bv, bv, bv, bv};
        #pragma unroll
        for (int rf = 0; rf < 4; ++rf) a2[rf][cf] = b4;
      }
      #pragma unroll
      for (int ks = 0; ks < 4; ++ks) {
        bf16x8 b0v = *(const bf16x8*)(W2 + (size_t)(wv * 32 + l15) * 128 + ks * 32 + hi8);
        bf16x8 b1v = *(const bf16x8*)(W2 + (size_t)(wv * 32 + 16 + l15) * 128 + ks * 32 + hi8);
        #pragma unroll
        for (int rf = 0; rf < 4; ++rf) {
          bf16x8 a = *(const bf16x8*)&h2[rf * 16 + l15][ks * 32 + hi8];
          a2[rf][0] = MFMA16(a, b0v, a2[rf][0]);
          a2[rf][1] = MFMA16(a, b1v, a2[rf][1]);
        }
      }
      #pragma unroll
      for (int cf = 0; cf < 2; ++cf)
        #pragma unroll
        for (int rf = 0; rf < 4; ++rf)
          #pragma unroll
          for (int r = 0; r < 4; ++r)
            out[(size_t)(m0 + rf * 16 + rloc + r) * 4096 + e * 256 + wv * 32 + cf * 16 + l15] =
                a2[rf][cf][r];
    }
    if (e < 15) {
      if (tid < 256) *(bf16x8*)&zsl[zrow][zc8] = zr;  // zsl last read in L0(e), 2 syncs ago
      __syncthreads();
    }
  }
}

// =============================== launcher ==================================
extern "C" void kernel_launch(void* const* d_in, const int* in_sizes, int n_in,
                              void* d_out, int out_size, void* d_ws, size_t ws_size,
                              hipStream_t stream) {
  (void)in_sizes; (void)n_in; (void)out_size; (void)ws_size;
  const float* x   = (const float*)d_in[0];
  const float* ew0 = (const float*)d_in[1];  const float* eb0 = (const float*)d_in[2];
  const float* ew1 = (const float*)d_in[3];  const float* eb1 = (const float*)d_in[4];
  const float* ew2 = (const float*)d_in[5];  const float* eb2 = (const float*)d_in[6];
  const float* dw0 = (const float*)d_in[7];  const float* db0 = (const float*)d_in[8];
  const float* dw1 = (const float*)d_in[9];  const float* db1 = (const float*)d_in[10];
  const float* dw2 = (const float*)d_in[11]; const float* db2 = (const float*)d_in[12];
  const float* cw[6]; const float* cb[6];
  for (int i = 0; i < 6; ++i) { cw[i] = (const float*)d_in[13 + 2 * i]; cb[i] = (const float*)d_in[14 + 2 * i]; }
  const float* xw[6]; const float* xb[6];
  for (int i = 0; i < 6; ++i) { xw[i] = (const float*)d_in[25 + 2 * i]; xb[i] = (const float*)d_in[26 + 2 * i]; }

  __bf16* wbuf   = (__bf16*)d_ws;
  __bf16* zstack = (__bf16*)((char*)d_ws + ZS_BYTES_OFF);  // z_stack, then z_stack_hat in-place
  float* out = (float*)d_out;

  prep_kernel<<<1024, 256, 0, stream>>>(ew0, ew1, ew2, dw0, dw1, dw2,
                                        cw[0], cw[1], cw[2], cw[3], cw[4], cw[5],
                                        xw[0], xw[1], xw[2], xw[3], xw[4], xw[5], wbuf);
  enc_kernel<<<512, 512, 0, stream>>>(x, wbuf, eb0, eb1, eb2, zstack);
  MidBias mb = {cb[0], cb[1], cb[2], cb[3], cb[4], cb[5],
                xb[0], xb[1], xb[2], xb[3], xb[4], xb[5]};
  mid_kernel<<<512, 512, 0, stream>>>(zstack, wbuf, mb, zstack);
  dec_kernel<<<512, 512, 0, stream>>>(zstack, wbuf, db0, db1, db2, out);
}